// Round 8
// baseline (838.118 us; speedup 1.0000x reference)
//
#include <hip/hip_runtime.h>
#include <hip/hip_cooperative_groups.h>

namespace cg = cooperative_groups;

#define N_NODES 100000
#define DEG 16
#define TPB 256
#define NTASK (N_NODES * 16)   // 1.6M lane-tasks per phase (16 lanes per row)

typedef _Float16 half_t;
typedef half_t h4 __attribute__((ext_vector_type(4)));
typedef float  v4f __attribute__((ext_vector_type(4)));

// ======================= fallback path (proven, round 5) =======================
__global__ __launch_bounds__(256) void cvt_f32_to_h(
    const v4f* __restrict__ x4, h4* __restrict__ xh)
{
    const int tid = blockIdx.x * blockDim.x + threadIdx.x;
    const v4f v = x4[tid];
    h4 h;
    h.x = (half_t)v.x; h.y = (half_t)v.y; h.z = (half_t)v.z; h.w = (half_t)v.w;
    xh[tid] = h;
}

__global__ __launch_bounds__(256) void hop_h2h(
    const h4* __restrict__ xh, const float* __restrict__ values,
    const int* __restrict__ indices, h4* __restrict__ outh)
{
    const int tid  = blockIdx.x * blockDim.x + threadIdx.x;
    const int row  = tid >> 4;
    const int lane = tid & 15;
    const int   my_idx = indices[row * DEG + lane];
    const float my_val = values[row * DEG + lane];
    v4f acc = {0.f, 0.f, 0.f, 0.f};
    #pragma unroll
    for (int j = 0; j < DEG; ++j) {
        const int   idx = __shfl(my_idx, j, 16);
        const float v   = __shfl(my_val, j, 16);
        const h4 hv = xh[(unsigned)idx * 16u + (unsigned)lane];
        acc.x += v * (float)hv.x; acc.y += v * (float)hv.y;
        acc.z += v * (float)hv.z; acc.w += v * (float)hv.w;
    }
    h4 ho;
    ho.x = (half_t)acc.x; ho.y = (half_t)acc.y;
    ho.z = (half_t)acc.z; ho.w = (half_t)acc.w;
    outh[row * 16 + lane] = ho;
}

__global__ __launch_bounds__(256) void hop_h2f(
    const h4* __restrict__ xh, const float* __restrict__ values,
    const int* __restrict__ indices, v4f* __restrict__ out4)
{
    const int tid  = blockIdx.x * blockDim.x + threadIdx.x;
    const int row  = tid >> 4;
    const int lane = tid & 15;
    const int   my_idx = indices[row * DEG + lane];
    const float my_val = values[row * DEG + lane];
    v4f acc = {0.f, 0.f, 0.f, 0.f};
    #pragma unroll
    for (int j = 0; j < DEG; ++j) {
        const int   idx = __shfl(my_idx, j, 16);
        const float v   = __shfl(my_val, j, 16);
        const h4 hv = xh[(unsigned)idx * 16u + (unsigned)lane];
        acc.x += v * (float)hv.x; acc.y += v * (float)hv.y;
        acc.z += v * (float)hv.z; acc.w += v * (float)hv.w;
    }
    out4[row * 16 + lane] = acc;
}

// ======================= fused cooperative path =======================
__device__ __forceinline__ void grid_sync_coherent(cg::grid_group& grid) {
    __builtin_amdgcn_fence(__ATOMIC_SEQ_CST, "agent");  // release: L2 writeback
    grid.sync();
    __builtin_amdgcn_fence(__ATOMIC_SEQ_CST, "agent");  // acquire: vL1/L2 invalidate
}

__global__ __launch_bounds__(TPB, 4) void propagate3(
    const float* __restrict__ x, const float* __restrict__ values,
    const int* __restrict__ indices, float* __restrict__ out,
    half_t* __restrict__ A, half_t* __restrict__ B)
{
    cg::grid_group grid = cg::this_grid();
    const int t0 = blockIdx.x * TPB + threadIdx.x;
    const int NT = gridDim.x * TPB;          // runtime grid size (1024/512/256 blocks)

    // phase 0: convert x (f32) -> A (fp16)
    {
        const v4f* x4 = (const v4f*)x;
        h4* a4 = (h4*)A;
        for (int i = t0; i < NTASK; i += NT) {
            const v4f v = x4[i];
            h4 h;
            h.x = (half_t)v.x; h.y = (half_t)v.y;
            h.z = (half_t)v.z; h.w = (half_t)v.w;
            a4[i] = h;
        }
    }
    grid_sync_coherent(grid);

    for (int hop = 0; hop < 3; ++hop) {
        const h4* s4 = (const h4*)((hop == 1) ? B : A);
        h4*      d4 = (h4*)((hop == 0) ? B : A);

        for (int i = t0; i < NTASK; i += NT) {
            const int   my_idx = indices[i];
            const float my_val = values[i];
            const int   lane   = i & 15;
            v4f acc = {0.f, 0.f, 0.f, 0.f};
            #pragma unroll
            for (int j = 0; j < DEG; ++j) {
                const int   idx = __shfl(my_idx, j, 16);
                const float v   = __shfl(my_val, j, 16);
                const h4 hv = s4[(unsigned)idx * 16u + (unsigned)lane];
                acc.x += v * (float)hv.x; acc.y += v * (float)hv.y;
                acc.z += v * (float)hv.z; acc.w += v * (float)hv.w;
            }
            if (hop == 2) {
                ((v4f*)out)[i] = acc;
            } else {
                h4 h;
                h.x = (half_t)acc.x; h.y = (half_t)acc.y;
                h.z = (half_t)acc.z; h.w = (half_t)acc.w;
                d4[i] = h;
            }
        }
        if (hop < 2) grid_sync_coherent(grid);
    }
}

extern "C" void kernel_launch(void* const* d_in, const int* in_sizes, int n_in,
                              void* d_out, int out_size, void* d_ws, size_t ws_size,
                              hipStream_t stream) {
    const float* x       = (const float*)d_in[0];
    const float* values  = (const float*)d_in[1];
    // d_in[2] = indptr (degenerate fixed-degree CSR) — unused
    const int*   indices = (const int*)d_in[3];

    float*  out = (float*)d_out;
    half_t* A   = (half_t*)d_ws;
    half_t* B   = (half_t*)((char*)d_ws + (size_t)N_NODES * 64 * sizeof(half_t));

    // Try the fused cooperative kernel; round 6/7 showed the unchecked launch
    // can fail silently (output == stub signature). Check the return code and
    // shrink the grid before falling back to the proven 4-kernel path.
    // Both paths are bitwise-identical per output element, so a path mismatch
    // between correctness call and captured graph is harmless.
    bool done = false;
    {
        void* args[] = { (void*)&x, (void*)&values, (void*)&indices,
                         (void*)&out, (void*)&A, (void*)&B };
        const int grids[3] = { 1024, 512, 256 };
        for (int g = 0; g < 3 && !done; ++g) {
            if (hipLaunchCooperativeKernel((void*)propagate3, dim3(grids[g]),
                                           dim3(TPB), args, 0, stream) == hipSuccess)
                done = true;
        }
    }

    if (!done) {
        const int block = 256;
        const int grid  = NTASK / block;   // 6250, exact
        cvt_f32_to_h<<<grid, block, 0, stream>>>((const v4f*)x, (h4*)A);
        hop_h2h<<<grid, block, 0, stream>>>((const h4*)A, values, indices, (h4*)B);
        hop_h2h<<<grid, block, 0, stream>>>((const h4*)B, values, indices, (h4*)A);
        hop_h2f<<<grid, block, 0, stream>>>((const h4*)A, values, indices, (v4f*)out);
    }
}

// Round 9
// 90.695 us; speedup vs baseline: 9.2411x; 9.2411x over previous
//
#include <hip/hip_runtime.h>

#define N_NODES 100000
#define DEG 16
// fp16 pipeline: row = 64 halfs = 128 B = exactly one cache line; 16 lanes/row,
// each lane owns 4 feats (8 B). Per-hop cost is set by the per-CU missed-line
// rate (~10.5 cyc/line, invariant across schedule/occupancy/MLP in rounds 1-5):
// 1.6M edges -> 1 line each -> 6250 lines/CU -> ~27 us/hop. fp16 halves f32's
// 2 lines/edge; accuracy margin 3x (absmax 0.5 vs threshold 1.5).

typedef _Float16 half_t;
typedef half_t h4 __attribute__((ext_vector_type(4)));
typedef float  v4f __attribute__((ext_vector_type(4)));

// ---- convert: f32 x -> fp16 buffer ----
__global__ __launch_bounds__(256) void cvt_f32_to_h(
    const v4f* __restrict__ x4, h4* __restrict__ xh)
{
    const int tid = blockIdx.x * blockDim.x + threadIdx.x;  // 1.6M threads, exact
    const v4f v = x4[tid];
    h4 h;
    h.x = (half_t)v.x; h.y = (half_t)v.y; h.z = (half_t)v.z; h.w = (half_t)v.w;
    xh[tid] = h;
}

// ---- hop: fp16 in, fp16 out (f32 accumulate) ----
__global__ __launch_bounds__(256) void hop_h2h(
    const h4*    __restrict__ xh,       // [N_NODES * 16] h4
    const float* __restrict__ values,   // [N_EDGES]
    const int*   __restrict__ indices,  // [N_EDGES]
    h4*          __restrict__ outh)     // [N_NODES * 16] h4
{
    const int tid  = blockIdx.x * blockDim.x + threadIdx.x;
    const int row  = tid >> 4;
    const int lane = tid & 15;

    const int   my_idx = indices[row * DEG + lane];   // coalesced
    const float my_val = values[row * DEG + lane];    // coalesced

    v4f acc = {0.f, 0.f, 0.f, 0.f};
    #pragma unroll
    for (int j = 0; j < DEG; ++j) {
        const int   idx = __shfl(my_idx, j, 16);
        const float v   = __shfl(my_val, j, 16);
        const h4 hv = xh[(unsigned)idx * 16u + (unsigned)lane]; // 1 line/row gather
        acc.x += v * (float)hv.x;
        acc.y += v * (float)hv.y;
        acc.z += v * (float)hv.z;
        acc.w += v * (float)hv.w;
    }
    h4 ho;
    ho.x = (half_t)acc.x; ho.y = (half_t)acc.y;
    ho.z = (half_t)acc.z; ho.w = (half_t)acc.w;
    outh[row * 16 + lane] = ho;
}

// ---- final hop: fp16 in, f32 out ----
__global__ __launch_bounds__(256) void hop_h2f(
    const h4*    __restrict__ xh,
    const float* __restrict__ values,
    const int*   __restrict__ indices,
    v4f*         __restrict__ out4)     // [N_NODES * 16] float4
{
    const int tid  = blockIdx.x * blockDim.x + threadIdx.x;
    const int row  = tid >> 4;
    const int lane = tid & 15;

    const int   my_idx = indices[row * DEG + lane];
    const float my_val = values[row * DEG + lane];

    v4f acc = {0.f, 0.f, 0.f, 0.f};
    #pragma unroll
    for (int j = 0; j < DEG; ++j) {
        const int   idx = __shfl(my_idx, j, 16);
        const float v   = __shfl(my_val, j, 16);
        const h4 hv = xh[(unsigned)idx * 16u + (unsigned)lane];
        acc.x += v * (float)hv.x;
        acc.y += v * (float)hv.y;
        acc.z += v * (float)hv.z;
        acc.w += v * (float)hv.w;
    }
    out4[row * 16 + lane] = acc;                      // 16B/lane, 256B/row coalesced
}

extern "C" void kernel_launch(void* const* d_in, const int* in_sizes, int n_in,
                              void* d_out, int out_size, void* d_ws, size_t ws_size,
                              hipStream_t stream) {
    const float* x       = (const float*)d_in[0];  // [N_NODES, 64] f32
    const float* values  = (const float*)d_in[1];  // [N_EDGES] f32
    // d_in[2] = indptr (degenerate fixed-degree CSR) — unused
    const int*   indices = (const int*)d_in[3];    // [N_EDGES] int32

    v4f* out = (v4f*)d_out;

    // ws layout: two fp16 ping-pong buffers of 12.8 MB each.
    h4* bufA = (h4*)d_ws;
    h4* bufB = (h4*)((char*)d_ws + (size_t)N_NODES * 64 * sizeof(half_t));

    const int block = 256;
    const int grid  = (N_NODES * 16) / block;   // 6250, exact

    // x (f32) -> bufA (fp16)
    cvt_f32_to_h<<<grid, block, 0, stream>>>((const v4f*)x, bufA);
    // hop 1: bufA -> bufB
    hop_h2h<<<grid, block, 0, stream>>>(bufA, values, indices, bufB);
    // hop 2: bufB -> bufA
    hop_h2h<<<grid, block, 0, stream>>>(bufB, values, indices, bufA);
    // hop 3: bufA -> d_out (f32)
    hop_h2f<<<grid, block, 0, stream>>>(bufA, values, indices, out);
}